// Round 1
// baseline (927.821 us; speedup 1.0000x reference)
//
#include <hip/hip_runtime.h>

// RGCN block-diagonal layer, f32.
// out = relu( (scatter_sum(msg) * norm) + bias + h @ loop_weight )
// msg[e, b*16+o] = sum_i h[src[e], b*16+i] * W[type[e], b*256 + i*16 + o]
//
// Phase A: init_kernel  : out[n][:] = bias + h[n] @ loop_weight   (LDS-staged LW)
// Phase B: edge_kernel  : out[dst][:] += msg * norm[dst]          (atomicAdd)
// Phase C: relu_kernel  : out = max(out, 0)                        (in place)

__global__ __launch_bounds__(256) void rgcn_init_kernel(
    const float* __restrict__ h, const float* __restrict__ loop_w,
    const float* __restrict__ bias, float* __restrict__ out, int N) {
  __shared__ float lw[128 * 128];  // 64 KB
  for (int idx = threadIdx.x; idx < 128 * 128 / 4; idx += 256) {
    ((float4*)lw)[idx] = ((const float4*)loop_w)[idx];
  }
  __syncthreads();

  const int lane = threadIdx.x & 63;
  const int wid = threadIdx.x >> 6;
  const int group0 = blockIdx.x * 4 + wid;
  const int ngroups = gridDim.x * 4;
  const int totgroups = (N + 3) >> 2;
  const float b0 = bias[lane];
  const float b1 = bias[64 + lane];

  for (int g = group0; g < totgroups; g += ngroups) {
    const int n0 = g * 4;
    const int nn = (N - n0 < 4) ? (N - n0) : 4;
    if (nn == 4) {
      const float* __restrict__ r0 = h + (size_t)n0 * 128;
      const float* __restrict__ r1 = r0 + 128;
      const float* __restrict__ r2 = r1 + 128;
      const float* __restrict__ r3 = r2 + 128;
      float a00 = b0, a01 = b1, a10 = b0, a11 = b1;
      float a20 = b0, a21 = b1, a30 = b0, a31 = b1;
#pragma unroll 4
      for (int k = 0; k < 128; ++k) {
        const float w0 = lw[k * 128 + lane];
        const float w1 = lw[k * 128 + 64 + lane];
        a00 = fmaf(r0[k], w0, a00); a01 = fmaf(r0[k], w1, a01);
        a10 = fmaf(r1[k], w0, a10); a11 = fmaf(r1[k], w1, a11);
        a20 = fmaf(r2[k], w0, a20); a21 = fmaf(r2[k], w1, a21);
        a30 = fmaf(r3[k], w0, a30); a31 = fmaf(r3[k], w1, a31);
      }
      float* __restrict__ o0 = out + (size_t)n0 * 128;
      o0[lane] = a00;        o0[64 + lane] = a01;
      o0[128 + lane] = a10;  o0[192 + lane] = a11;
      o0[256 + lane] = a20;  o0[320 + lane] = a21;
      o0[384 + lane] = a30;  o0[448 + lane] = a31;
    } else {
      for (int r = 0; r < nn; ++r) {
        const int n = n0 + r;
        const float* __restrict__ hr = h + (size_t)n * 128;
        float a0 = b0, a1 = b1;
#pragma unroll 4
        for (int k = 0; k < 128; ++k) {
          const float a = hr[k];
          a0 = fmaf(a, lw[k * 128 + lane], a0);
          a1 = fmaf(a, lw[k * 128 + 64 + lane], a1);
        }
        out[(size_t)n * 128 + lane] = a0;
        out[(size_t)n * 128 + 64 + lane] = a1;
      }
    }
  }
}

__global__ __launch_bounds__(256) void rgcn_edge_kernel(
    const float* __restrict__ h, const float* __restrict__ norm,
    const int* __restrict__ esrc, const int* __restrict__ edst,
    const int* __restrict__ etype, const float* __restrict__ weight,
    float* __restrict__ out, int E) {
  const int lane = threadIdx.x & 63;
  const int wid = threadIdx.x >> 6;
  const int wave0 = blockIdx.x * 4 + wid;
  const int nwaves = gridDim.x * 4;
  const int b = lane >> 4;   // base index for first half (0..3)
  const int o = lane & 15;   // output col within block

  for (int e = wave0; e < E; e += nwaves) {
    const int src = esrc[e];
    const int dst = edst[e];
    const int et = etype[e];

    // coalesced load of the source node's 128-float row (2 dwords/lane)
    const float s_lo = h[src * 128 + lane];
    const float s_hi = h[src * 128 + 64 + lane];
    const float nrm = norm[dst];

    // W[et][b][i][o] at et*2048 + b*256 + i*16 + o ; second half uses b+4.
    const float* __restrict__ Wb = weight + et * 2048 + b * 256 + o;

    float m0 = 0.f, m1 = 0.f;
#pragma unroll
    for (int i = 0; i < 16; ++i) {
      // src[b*16+i] lives in lane (b*16+i) = (lane&48)+i of s_lo / s_hi
      const float a_lo = __shfl(s_lo, (lane & 48) + i, 64);
      const float a_hi = __shfl(s_hi, (lane & 48) + i, 64);
      m0 = fmaf(a_lo, Wb[i * 16], m0);
      m1 = fmaf(a_hi, Wb[1024 + i * 16], m1);
    }

    atomicAdd(&out[dst * 128 + lane], m0 * nrm);
    atomicAdd(&out[dst * 128 + 64 + lane], m1 * nrm);
  }
}

__global__ __launch_bounds__(256) void rgcn_relu_kernel(float* __restrict__ out,
                                                        int total4) {
  int i = blockIdx.x * 256 + threadIdx.x;
  const int stride = gridDim.x * 256;
  for (; i < total4; i += stride) {
    float4 v = ((float4*)out)[i];
    v.x = fmaxf(v.x, 0.f);
    v.y = fmaxf(v.y, 0.f);
    v.z = fmaxf(v.z, 0.f);
    v.w = fmaxf(v.w, 0.f);
    ((float4*)out)[i] = v;
  }
}

extern "C" void kernel_launch(void* const* d_in, const int* in_sizes, int n_in,
                              void* d_out, int out_size, void* d_ws, size_t ws_size,
                              hipStream_t stream) {
  const float* h      = (const float*)d_in[0];
  const float* norm   = (const float*)d_in[1];
  const int*   esrc   = (const int*)d_in[2];
  const int*   edst   = (const int*)d_in[3];
  const int*   etype  = (const int*)d_in[4];
  const float* weight = (const float*)d_in[5];
  const float* bias   = (const float*)d_in[6];
  const float* loop_w = (const float*)d_in[7];
  float* out = (float*)d_out;

  const int N = in_sizes[0] / 128;
  const int E = in_sizes[2];

  rgcn_init_kernel<<<2048, 256, 0, stream>>>(h, loop_w, bias, out, N);
  rgcn_edge_kernel<<<4096, 256, 0, stream>>>(h, norm, esrc, edst, etype, weight,
                                             out, E);
  rgcn_relu_kernel<<<2048, 256, 0, stream>>>(out, (N * 128) / 4);
}